// Round 1
// baseline (99.050 us; speedup 1.0000x reference)
//
#include <hip/hip_runtime.h>
#include <math.h>

#define GRID_DIM 128
#define NPIX (GRID_DIM * GRID_DIM)   // 16384
#define NPTS 2048
#define NSEG (NPTS - 1)              // 2047
#define CHUNK 128
#define NCHUNK 16                    // 16*128 = 2048 >= 2047
#define GAMMA_F 200.0f

// ws layout: unsigned int min_bits[2][NPIX]  (bit pattern of fp32 min d^2)
// [0] = pred, [1] = gt

__global__ __launch_bounds__(256) void dist_min_kernel(
    const float* __restrict__ pred, const float* __restrict__ gt,
    unsigned int* __restrict__ ws_min)
{
    // Segment data staged in LDS; all lanes read same segment -> broadcast,
    // conflict-free.
    __shared__ float4 s_seg[2][CHUNK];   // pjx, pjy, vx, vy
    __shared__ float  s_inv[2][CHUNK];   // 1/|v|^2 (0 if degenerate/masked)

    const int tid = threadIdx.x;
    const int chunk = blockIdx.y;

    // ---- stage: threads 0..127 -> pred segments, 128..255 -> gt segments
    {
        const int t  = tid >> 7;       // 0 = pred, 1 = gt
        const int sl = tid & 127;
        const int s  = chunk * CHUNK + sl;
        float pjx, pjy, vx, vy, inv;
        if (s < NSEG) {
            const float* src = t ? gt : pred;
            const float pix_ = (src[3 * s + 0] - 0.5f) * 2.0f;
            const float piy_ = (src[3 * s + 1] - 0.5f) * 2.0f;
            const float pen  =  src[3 * s + 2];
            pjx = (src[3 * s + 3] - 0.5f) * 2.0f;
            pjy = (src[3 * s + 4] - 0.5f) * 2.0f;
            // gt mask: pen != 0 ; pred mask: pen > 0.5  (segment dropped if
            // its FIRST point is masked, per mask[:-1])
            const bool masked = t ? (pen != 0.0f) : (pen > 0.5f);
            vx = pix_ - pjx;
            vy = piy_ - pjy;
            const float vn = vx * vx + vy * vy;
            inv = (vn == 0.0f) ? 0.0f : (1.0f / vn);   // vn==0 -> diff = u
            if (masked) { pjx = 1e15f; pjy = 1e15f; vx = 0.0f; vy = 0.0f; inv = 0.0f; }
        } else {
            // pad segment: contributes d^2 ~ 2e30, never wins the min
            pjx = 1e15f; pjy = 1e15f; vx = 0.0f; vy = 0.0f; inv = 0.0f;
        }
        s_seg[t][sl] = make_float4(pjx, pjy, vx, vy);
        s_inv[t][sl] = inv;
    }
    __syncthreads();

    const int p = blockIdx.x * 256 + tid;
    const int w = p & (GRID_DIM - 1);
    const int h = p >> 7;
    // match reference rounding: x/127*2-1
    const float gx = (float)w / 127.0f * 2.0f - 1.0f;
    const float gy = (float)h / 127.0f * 2.0f - 1.0f;

    #pragma unroll
    for (int t = 0; t < 2; ++t) {
        float m = 3.0e38f;
        #pragma unroll 8
        for (int s = 0; s < CHUNK; ++s) {
            const float4 sg = s_seg[t][s];
            const float inv = s_inv[t][s];
            const float ux = gx - sg.x;
            const float uy = gy - sg.y;
            const float uv = fmaf(ux, sg.z, uy * sg.w);
            float rs = uv * inv;
            rs = fminf(fmaxf(rs, 0.0f), 1.0f);          // clamp [0,1] (med3)
            const float dx = fmaf(-rs, sg.z, ux);
            const float dy = fmaf(-rs, sg.w, uy);
            const float d2 = fmaf(dx, dx, dy * dy);
            m = fminf(m, d2);
        }
        // d^2 >= 0 -> IEEE bit pattern is monotone as unsigned
        atomicMin(&ws_min[t * NPIX + p], __float_as_uint(m));
    }
}

__global__ __launch_bounds__(1024) void dist_reduce_kernel(
    const float* __restrict__ ws_min, float* __restrict__ out)
{
    __shared__ float s_part[16];
    const int tid = threadIdx.x;
    float acc = 0.0f;
    #pragma unroll
    for (int i = 0; i < NPIX / 1024; ++i) {
        const int p = i * 1024 + tid;
        const float mp = ws_min[p];
        const float mg = ws_min[NPIX + p];
        const float pd = expf(-GAMMA_F * mp);   // min=inf-ish -> 0, as ref
        const float gd = expf(-GAMMA_F * mg);
        const float d = pd - gd;
        acc = fmaf(d, d, acc);
    }
    // wave64 reduce
    #pragma unroll
    for (int off = 32; off > 0; off >>= 1)
        acc += __shfl_down(acc, off, 64);
    if ((tid & 63) == 0) s_part[tid >> 6] = acc;
    __syncthreads();
    if (tid == 0) {
        float total = 0.0f;
        #pragma unroll
        for (int i = 0; i < 16; ++i) total += s_part[i];
        out[0] = total * (1.0f / (float)NPIX);
    }
}

extern "C" void kernel_launch(void* const* d_in, const int* in_sizes, int n_in,
                              void* d_out, int out_size, void* d_ws, size_t ws_size,
                              hipStream_t stream)
{
    const float* pred = (const float*)d_in[0];
    const float* gt   = (const float*)d_in[1];
    unsigned int* ws_min = (unsigned int*)d_ws;

    // init mins to 0xFFFFFFFF (> any non-negative float bit pattern)
    hipMemsetAsync(d_ws, 0xFF, (size_t)2 * NPIX * sizeof(unsigned int), stream);

    dim3 grid(NPIX / 256, NCHUNK);
    dist_min_kernel<<<grid, 256, 0, stream>>>(pred, gt, ws_min);

    dist_reduce_kernel<<<1, 1024, 0, stream>>>((const float*)d_ws, (float*)d_out);
}

// Round 2
// 74.188 us; speedup vs baseline: 1.3351x; 1.3351x over previous
//
#include <hip/hip_runtime.h>
#include <math.h>

#define GRID_DIM 128
#define NPIX 16384
#define NSEG 2047
#define NSEGP 2048
#define CHUNK 128
#define NCHUNK 16
// raw-coordinate space: u,v scale by 2 vs reference -> d2 scales by 4.
// gamma_eff = 200 * 4 = 800, applied in the reduce kernel.
#define GAMMA4 800.0f

typedef float v2f __attribute__((ext_vector_type(2)));

// ws layout (floats/uints):
//   [0, 2*NPIX)                      : min d^2 bit patterns [2][NPIX]
//   [2*NPIX, 2*NPIX + 5*2*NSEGP)     : segment SoA: pjx,pjy,vx,vy,inv  [5][2][NSEGP]
#define SEG_OFF (2 * NPIX)
#define ARR(k) (SEG_OFF + (k) * 2 * NSEGP)

// ---- setup: init min buffer + precompute segment SoA (raw coord space)
__global__ __launch_bounds__(256) void setup_kernel(
    const float* __restrict__ pred, const float* __restrict__ gt,
    float* __restrict__ ws)
{
    const int tid = blockIdx.x * 256 + threadIdx.x;   // [0, 4096)

    // init mins: 2*NPIX = 32768 uints, 8 per thread as 2x uint4
    {
        uint4* minp = (uint4*)ws;
        const uint4 big = make_uint4(0x7f7fffffu, 0x7f7fffffu, 0x7f7fffffu, 0x7f7fffffu);
        minp[tid * 2 + 0] = big;
        minp[tid * 2 + 1] = big;
    }

    // one segment slot per thread: t = pred/gt, s = segment index (pad at 2047)
    const int t = tid >> 11;          // 0 = pred, 1 = gt
    const int s = tid & (NSEGP - 1);
    float pjx, pjy, vx, vy, inv;
    if (s < NSEG) {
        const float* src = t ? gt : pred;
        const float pix_ = src[3 * s + 0];
        const float piy_ = src[3 * s + 1];
        const float pen  = src[3 * s + 2];
        pjx = src[3 * s + 3];
        pjy = src[3 * s + 4];
        // segment s dropped if point s is masked (mask[:-1])
        const bool masked = t ? (pen != 0.0f) : (pen > 0.5f);
        vx = pix_ - pjx;
        vy = piy_ - pjy;
        const float vn = vx * vx + vy * vy;
        inv = (vn == 0.0f) ? 0.0f : (1.0f / vn);   // vn==0 -> diff = u (ref semantics)
        if (masked) { pjx = 1e15f; pjy = 1e15f; vx = 0.0f; vy = 0.0f; inv = 0.0f; }
    } else {
        // pad: d^2 ~ 2e30 -> exp(-800*d^2) = 0, never wins a real min
        pjx = 1e15f; pjy = 1e15f; vx = 0.0f; vy = 0.0f; inv = 0.0f;
    }
    ws[ARR(0) + t * NSEGP + s] = pjx;
    ws[ARR(1) + t * NSEGP + s] = pjy;
    ws[ARR(2) + t * NSEGP + s] = vx;
    ws[ARR(3) + t * NSEGP + s] = vy;
    ws[ARR(4) + t * NSEGP + s] = inv;
}

// ---- main: min point-to-segment d^2 per pixel, chunked over segments
__global__ __launch_bounds__(256) void dist_min_kernel(
    const float* __restrict__ ws_seg, unsigned int* __restrict__ ws_min)
{
    const int tid = threadIdx.x;
    const int p = blockIdx.x * 256 + tid;
    const int chunk = blockIdx.y;
    // raw-space grid coords: x/127 in [0,1]
    const float gx = (float)(p & (GRID_DIM - 1)) * (1.0f / 127.0f);
    const float gy = (float)(p >> 7) * (1.0f / 127.0f);
    const v2f gx2 = {gx, gx};
    const v2f gy2 = {gy, gy};

    #pragma unroll
    for (int t = 0; t < 2; ++t) {
        // SoA pair pointers — addresses are wave-uniform -> scalar loads
        const v2f* pjx = (const v2f*)(ws_seg + ARR(0) + t * NSEGP);
        const v2f* pjy = (const v2f*)(ws_seg + ARR(1) + t * NSEGP);
        const v2f* vx  = (const v2f*)(ws_seg + ARR(2) + t * NSEGP);
        const v2f* vy  = (const v2f*)(ws_seg + ARR(3) + t * NSEGP);
        const v2f* inv = (const v2f*)(ws_seg + ARR(4) + t * NSEGP);
        const int base = chunk * (CHUNK / 2);   // in segment-pairs

        float m = 3.0e38f;
        #pragma unroll 4
        for (int i = 0; i < CHUNK / 2; ++i) {
            const v2f PJX = pjx[base + i];
            const v2f PJY = pjy[base + i];
            const v2f VX  = vx[base + i];
            const v2f VY  = vy[base + i];
            const v2f INV = inv[base + i];
            // packed fp32 (v_pk_add/mul/fma) over 2 segments
            v2f ux = gx2 - PJX;
            v2f uy = gy2 - PJY;
            v2f uv = ux * VX + uy * VY;
            v2f rs = uv * INV;
            rs.x = fminf(fmaxf(rs.x, 0.0f), 1.0f);   // v_med3 per half
            rs.y = fminf(fmaxf(rs.y, 0.0f), 1.0f);
            v2f dx = ux - rs * VX;
            v2f dy = uy - rs * VY;
            v2f d2 = dx * dx + dy * dy;
            m = fminf(m, fminf(d2.x, d2.y));          // v_min3
        }
        // d^2 >= 0 -> IEEE bits monotone as unsigned
        atomicMin(&ws_min[t * NPIX + p], __float_as_uint(m));
    }
}

// ---- reduce: exp(-800*d2_raw) for both transforms, MSE over pixels
__global__ __launch_bounds__(1024) void dist_reduce_kernel(
    const float* __restrict__ ws_min, float* __restrict__ out)
{
    __shared__ float s_part[16];
    const int tid = threadIdx.x;
    float acc = 0.0f;
    #pragma unroll
    for (int i = 0; i < NPIX / 1024; ++i) {
        const int p = i * 1024 + tid;
        const float mp = ws_min[p];
        const float mg = ws_min[NPIX + p];
        const float pd = __expf(-GAMMA4 * mp);
        const float gd = __expf(-GAMMA4 * mg);
        const float d = pd - gd;
        acc = fmaf(d, d, acc);
    }
    #pragma unroll
    for (int off = 32; off > 0; off >>= 1)
        acc += __shfl_down(acc, off, 64);
    if ((tid & 63) == 0) s_part[tid >> 6] = acc;
    __syncthreads();
    if (tid == 0) {
        float total = 0.0f;
        #pragma unroll
        for (int i = 0; i < 16; ++i) total += s_part[i];
        out[0] = total * (1.0f / (float)NPIX);
    }
}

extern "C" void kernel_launch(void* const* d_in, const int* in_sizes, int n_in,
                              void* d_out, int out_size, void* d_ws, size_t ws_size,
                              hipStream_t stream)
{
    const float* pred = (const float*)d_in[0];
    const float* gt   = (const float*)d_in[1];
    float* ws = (float*)d_ws;

    setup_kernel<<<16, 256, 0, stream>>>(pred, gt, ws);

    dim3 grid(NPIX / 256, NCHUNK);
    dist_min_kernel<<<grid, 256, 0, stream>>>(ws, (unsigned int*)d_ws);

    dist_reduce_kernel<<<1, 1024, 0, stream>>>(ws, (float*)d_out);
}